// Round 5
// baseline (17.134 us; speedup 1.0000x reference)
//
#include <hip/hip_runtime.h>
#include <cmath>

// Problem constants (fixed by the reference)
#define B_ 256
#define I_ 1024
#define O_ 1024

typedef __attribute__((ext_vector_type(8))) short short8;   // 8 bf16 = 4 VGPRs
typedef __attribute__((ext_vector_type(4))) float f32x4;

// float -> bf16 bits, round-to-nearest-even (inputs are finite)
__device__ inline unsigned short f2bf(float f) {
  union { float f; unsigned u; } c;
  c.f = f;
  unsigned u = c.u;
  return (unsigned short)((u + 0x7FFFu + ((u >> 16) & 1u)) >> 16);
}

// fast log(tanh(100|x|)) via hardware exp/log:
//   log(tanh z) = log((1 - e^-2z) / (1 + e^-2z))
// x==0: e^0=1 -> log(0) = -inf -> clamped to -1e30 (exp(-1e30)=0 later).
// Relative error ~1e-6 << bf16 rounding (4e-3).
__device__ inline float fast_lt(float x) {
  float z = 100.0f * fabsf(x);
  float t = __expf(-2.0f * z);
  float lt = __logf((1.0f - t) / (1.0f + t));
  return fmaxf(lt, -1e30f);
}

#define WBLKS ((O_ * I_) / 2048)   // 512 blocks for weight prep
#define XBLKS ((B_ * I_) / 2048)   // 128 blocks for x prep

// ---------------------------------------------------------------------------
// Merged prep (one launch):
//   blocks [0, WBLKS):     wb = bf16(fc * (vw>0)), mb = bf16(vw>0)
//   blocks [WBLKS, +XBLKS): xb = bf16(x), ltb = bf16(log(tanh(100|x|)))
// ---------------------------------------------------------------------------
__global__ __launch_bounds__(256) void prep_all(
    const float* __restrict__ x, const float* __restrict__ vw,
    const float* __restrict__ fcw, unsigned short* __restrict__ xb,
    unsigned short* __restrict__ ltb, unsigned short* __restrict__ wb,
    unsigned short* __restrict__ mb) {
  const int bid = blockIdx.x;
  if (bid < WBLKS) {
    int idx = (bid * 256 + threadIdx.x) * 8;
    float4 v0 = *reinterpret_cast<const float4*>(vw + idx);
    float4 v1 = *reinterpret_cast<const float4*>(vw + idx + 4);
    float4 f0 = *reinterpret_cast<const float4*>(fcw + idx);
    float4 f1 = *reinterpret_cast<const float4*>(fcw + idx + 4);
    float va[8] = {v0.x, v0.y, v0.z, v0.w, v1.x, v1.y, v1.z, v1.w};
    float fa[8] = {f0.x, f0.y, f0.z, f0.w, f1.x, f1.y, f1.z, f1.w};
    short8 wv, mv;
#pragma unroll
    for (int j = 0; j < 8; ++j) {
      bool m = va[j] > 0.0f;
      wv[j] = (short)f2bf(m ? fa[j] : 0.0f);
      mv[j] = (short)(m ? 0x3F80 : 0x0000);  // bf16 1.0 / 0.0
    }
    *reinterpret_cast<short8*>(wb + idx) = wv;
    *reinterpret_cast<short8*>(mb + idx) = mv;
  } else {
    int idx = ((bid - WBLKS) * 256 + threadIdx.x) * 8;
    float4 x0 = *reinterpret_cast<const float4*>(x + idx);
    float4 x1 = *reinterpret_cast<const float4*>(x + idx + 4);
    float xa[8] = {x0.x, x0.y, x0.z, x0.w, x1.x, x1.y, x1.z, x1.w};
    short8 xv, lv;
#pragma unroll
    for (int j = 0; j < 8; ++j) {
      xv[j] = (short)f2bf(xa[j]);
      lv[j] = (short)f2bf(fast_lt(xa[j]));
    }
    *reinterpret_cast<short8*>(xb + idx) = xv;
    *reinterpret_cast<short8*>(ltb + idx) = lv;
  }
}

// ---------------------------------------------------------------------------
// Fused dual MFMA GEMM with intra-block split-K, BK=128.
// Tile 32(M) x 32(N); 512 threads = 8 waves. Wave-group kg = wid>>2 handles
// K-half [kg*512, +512) in 4 iterations of BK=128; within a group the 4
// waves form a 2x2 fragment grid. Register prefetch (8x short8) double-
// stages each group's LDS. Cross-group combine: 8KB LDS reduce (reusing As)
// fused with the exp/relu epilogue.
// 136-short rows (272B = 17x16B): fragment b128 reads and staging stores
// land 8 dwords/bank exactly -> conflict-free.
// ---------------------------------------------------------------------------
__global__ __launch_bounds__(512) void mfma_fused3(
    const unsigned short* __restrict__ xb, const unsigned short* __restrict__ ltb,
    const unsigned short* __restrict__ wb, const unsigned short* __restrict__ mb,
    float* __restrict__ out) {
  const int on0 = blockIdx.x * 32;
  const int bm0 = blockIdx.y * 32;

  __shared__ short As[2][32][136];
  __shared__ short Ls[2][32][136];
  __shared__ short Ws[2][32][136];
  __shared__ short Ms[2][32][136];

  const int t = threadIdx.x;
  const int lane = t & 63;
  const int wid = t >> 6;            // 0..7
  const int kg = wid >> 2;           // K-group (0: k<512, 1: k>=512)
  const int wm = (wid >> 1) & 1, wn = wid & 1;
  const int lr = lane & 15;
  const int lk = (lane >> 4) * 8;

  const int tl = t & 255;            // thread index within group
  const int srow = tl >> 4;          // staging rows: srow and srow+16
  const int scol = (tl & 15) * 8;    // staging col (elems), 0..120

  const size_t aoff = (size_t)(bm0 + srow) * I_ + kg * 512 + scol;
  const size_t boff = (size_t)(on0 + srow) * I_ + kg * 512 + scol;
  const size_t rstep = (size_t)16 * I_;  // +16 rows

  // prefetch tile 0 of this group's K-half (4 streams x 2 rows)
  short8 rx0 = *reinterpret_cast<const short8*>(xb + aoff);
  short8 rx1 = *reinterpret_cast<const short8*>(xb + aoff + rstep);
  short8 rl0 = *reinterpret_cast<const short8*>(ltb + aoff);
  short8 rl1 = *reinterpret_cast<const short8*>(ltb + aoff + rstep);
  short8 rw0 = *reinterpret_cast<const short8*>(wb + boff);
  short8 rw1 = *reinterpret_cast<const short8*>(wb + boff + rstep);
  short8 rm0 = *reinterpret_cast<const short8*>(mb + boff);
  short8 rm1 = *reinterpret_cast<const short8*>(mb + boff + rstep);

  f32x4 accd = {0.f, 0.f, 0.f, 0.f};
  f32x4 accs = {0.f, 0.f, 0.f, 0.f};

  for (int kt = 0; kt < 512; kt += 128) {
    __syncthreads();  // previous iter's LDS reads done before overwrite
    *reinterpret_cast<short8*>(&As[kg][srow][scol]) = rx0;
    *reinterpret_cast<short8*>(&As[kg][srow + 16][scol]) = rx1;
    *reinterpret_cast<short8*>(&Ls[kg][srow][scol]) = rl0;
    *reinterpret_cast<short8*>(&Ls[kg][srow + 16][scol]) = rl1;
    *reinterpret_cast<short8*>(&Ws[kg][srow][scol]) = rw0;
    *reinterpret_cast<short8*>(&Ws[kg][srow + 16][scol]) = rw1;
    *reinterpret_cast<short8*>(&Ms[kg][srow][scol]) = rm0;
    *reinterpret_cast<short8*>(&Ms[kg][srow + 16][scol]) = rm1;
    if (kt + 128 < 512) {  // issue next-tile loads; latency hides under MFMA
      rx0 = *reinterpret_cast<const short8*>(xb + aoff + kt + 128);
      rx1 = *reinterpret_cast<const short8*>(xb + aoff + rstep + kt + 128);
      rl0 = *reinterpret_cast<const short8*>(ltb + aoff + kt + 128);
      rl1 = *reinterpret_cast<const short8*>(ltb + aoff + rstep + kt + 128);
      rw0 = *reinterpret_cast<const short8*>(wb + boff + kt + 128);
      rw1 = *reinterpret_cast<const short8*>(wb + boff + rstep + kt + 128);
      rm0 = *reinterpret_cast<const short8*>(mb + boff + kt + 128);
      rm1 = *reinterpret_cast<const short8*>(mb + boff + rstep + kt + 128);
    }
    __syncthreads();
#pragma unroll
    for (int ks = 0; ks < 4; ++ks) {
      const int kb = ks * 32 + lk;
      short8 af = *reinterpret_cast<const short8*>(&As[kg][wm * 16 + lr][kb]);
      short8 lf = *reinterpret_cast<const short8*>(&Ls[kg][wm * 16 + lr][kb]);
      short8 wf = *reinterpret_cast<const short8*>(&Ws[kg][wn * 16 + lr][kb]);
      short8 mf = *reinterpret_cast<const short8*>(&Ms[kg][wn * 16 + lr][kb]);
      accd = __builtin_amdgcn_mfma_f32_16x16x32_bf16(af, wf, accd, 0, 0, 0);
      accs = __builtin_amdgcn_mfma_f32_16x16x32_bf16(lf, mf, accs, 0, 0, 0);
    }
  }

  // Cross-group reduce (group 1 -> LDS, group 0 adds) + fused epilogue.
  __syncthreads();
  float* red = reinterpret_cast<float*>(&As[0][0][0]);  // 8KB needed, 17KB avail
  const int ridx = ((wid & 3) * 64 + lane) * 8;
  if (kg == 1) {
#pragma unroll
    for (int r = 0; r < 4; ++r) {
      red[ridx + r] = accd[r];
      red[ridx + 4 + r] = accs[r];
    }
  }
  __syncthreads();
  if (kg == 0) {
    // C/D layout: col = lane&15, row = (lane>>4)*4 + reg   [m89-verified]
    const int orow = bm0 + wm * 16 + (lane >> 4) * 4;
    const int ocol = on0 + wn * 16 + lr;
#pragma unroll
    for (int r = 0; r < 4; ++r) {
      float dsum = accd[r] + red[ridx + r];
      float ssum = accs[r] + red[ridx + 4 + r];
      float d = __expf(ssum);
      float y = fmaxf(dsum * d, 0.0f);
      size_t off = (size_t)(orow + r) * O_ + ocol;
      out[off] = y;
      out[(size_t)B_ * O_ + off] = d;
    }
  }
}

// ---------------------------------------------------------------------------
// fp32 fallback (workspace too small): inline log-tanh, fused epilogue
// ---------------------------------------------------------------------------
__global__ __launch_bounds__(256) void dual_gemm_f32(
    const float* __restrict__ x, const float* __restrict__ vw,
    const float* __restrict__ fcw, float* __restrict__ out) {
  const int on0 = blockIdx.x * 64;
  const int bm0 = blockIdx.y * 64;
  __shared__ float xs[32][68];
  __shared__ float ls[32][68];
  __shared__ float wsm[32][68];
  __shared__ float msh[32][68];
  const int t = threadIdx.x;
  const int tx = t & 15, ty = t >> 4;
  const int m0 = ty * 4, n0 = tx * 4;
  float accd[4][4] = {{0.f}};
  float accs[4][4] = {{0.f}};
  for (int kt = 0; kt < I_; kt += 32) {
#pragma unroll
    for (int j = 0; j < 8; ++j) {
      int f = j * 256 + t;
      int m = f >> 5;
      int kk = f & 31;
      int gk = kt + kk;
      float xv = x[(size_t)(bm0 + m) * I_ + gk];
      xs[kk][m] = xv;
      ls[kk][m] = fast_lt(xv);
      float vv = vw[(size_t)(on0 + m) * I_ + gk];
      float fv = fcw[(size_t)(on0 + m) * I_ + gk];
      float mk = vv > 0.0f ? 1.0f : 0.0f;
      wsm[kk][m] = fv * mk;
      msh[kk][m] = mk;
    }
    __syncthreads();
#pragma unroll
    for (int kk = 0; kk < 32; ++kk) {
      float4 xv = *reinterpret_cast<const float4*>(&xs[kk][m0]);
      float4 lv = *reinterpret_cast<const float4*>(&ls[kk][m0]);
      float4 wv = *reinterpret_cast<const float4*>(&wsm[kk][n0]);
      float4 mv = *reinterpret_cast<const float4*>(&msh[kk][n0]);
      float xa[4] = {xv.x, xv.y, xv.z, xv.w};
      float la[4] = {lv.x, lv.y, lv.z, lv.w};
      float wa[4] = {wv.x, wv.y, wv.z, wv.w};
      float ma[4] = {mv.x, mv.y, mv.z, mv.w};
#pragma unroll
      for (int i = 0; i < 4; ++i)
#pragma unroll
        for (int j = 0; j < 4; ++j) {
          accd[i][j] = fmaf(xa[i], wa[j], accd[i][j]);
          accs[i][j] = fmaf(la[i], ma[j], accs[i][j]);
        }
    }
    __syncthreads();
  }
#pragma unroll
  for (int i = 0; i < 4; ++i) {
    int row = bm0 + m0 + i;
#pragma unroll
    for (int j = 0; j < 4; ++j) {
      float delta = __expf(accs[i][j]);
      out[(size_t)row * O_ + on0 + n0 + j] = fmaxf(accd[i][j] * delta, 0.0f);
      out[(size_t)B_ * O_ + (size_t)row * O_ + on0 + n0 + j] = delta;
    }
  }
}

extern "C" void kernel_launch(void* const* d_in, const int* in_sizes, int n_in,
                              void* d_out, int out_size, void* d_ws,
                              size_t ws_size, hipStream_t stream) {
  const float* x = (const float*)d_in[0];
  const float* vw = (const float*)d_in[1];
  const float* fcw = (const float*)d_in[2];
  float* out = (float*)d_out;

  const size_t xbB = (size_t)B_ * I_ * 2;  // 512 KB
  const size_t wbB = (size_t)O_ * I_ * 2;  // 2 MB
  const size_t bfB = 2 * xbB + 2 * wbB;    // 5 MB total

  unsigned short* xb = (unsigned short*)d_ws;
  unsigned short* ltb = (unsigned short*)((char*)d_ws + xbB);
  unsigned short* wb = (unsigned short*)((char*)d_ws + 2 * xbB);
  unsigned short* mb = (unsigned short*)((char*)d_ws + 2 * xbB + wbB);

  if (ws_size >= bfB) {
    prep_all<<<WBLKS + XBLKS, 256, 0, stream>>>(x, vw, fcw, xb, ltb, wb, mb);
    mfma_fused3<<<dim3(O_ / 32, B_ / 32), 512, 0, stream>>>(xb, ltb, wb, mb, out);
  } else {
    dual_gemm_f32<<<dim3(O_ / 64, B_ / 64, 1), 256, 0, stream>>>(x, vw, fcw, out);
  }
}